// Round 16
// baseline (385.487 us; speedup 1.0000x reference)
//
#include <hip/hip_runtime.h>

#define NN   102400
#define EE   819200
#define GG   512
#define NPG  200
#define DD   128
#define TT   64
#define BB   8
#define LL   4
#define NB_A   320     // CSR-build blocks
#define ECH_A  2560    // edges per CSR-build block (EE / NB_A)
#define SCAP 2560      // per-graph sorted-edge LDS capacity
#define NSLOT 16       // slot 0 = self, 1..15 edges, overflow list beyond
#define CHK  25        // nodes per agg chunk (8 per graph)

typedef unsigned int uint;

static __device__ __forceinline__ void wave_sum64_2(float& a, float& b) {
#pragma unroll
    for (int off = 32; off > 0; off >>= 1) {
        a += __shfl_xor(a, off, 64);
        b += __shfl_xor(b, off, 64);
    }
}

// ---------------- CSR build: coalesced two-level counting sort ----------------

__global__ __launch_bounds__(256) void k_a1(const int* __restrict__ src,
                                            int* __restrict__ hist) {
    __shared__ int h[GG];
    int tid = threadIdx.x;
    h[tid] = 0; h[tid + 256] = 0;
    __syncthreads();
    int base = blockIdx.x * ECH_A;
#pragma unroll
    for (int it = 0; it < ECH_A / 256; ++it)
        atomicAdd(&h[src[base + it * 256 + tid] / NPG], 1);
    __syncthreads();
    hist[blockIdx.x * GG + tid] = h[tid];
    hist[blockIdx.x * GG + tid + 256] = h[tid + 256];
}

__global__ __launch_bounds__(512) void k_a2(const int* __restrict__ hist,
                                            int* __restrict__ off2,
                                            int* __restrict__ goff) {
    __shared__ int sm[GG];
    int g = threadIdx.x;
    int s = 0;
    for (int b = 0; b < NB_A; ++b) s += hist[b * GG + g];
    sm[g] = s;
    __syncthreads();
    for (int d = 1; d < GG; d <<= 1) {
        int v = (g >= d) ? sm[g - d] : 0;
        __syncthreads();
        sm[g] += v;
        __syncthreads();
    }
    int base = sm[g] - s;
    goff[g] = base;
    if (g == GG - 1) goff[GG] = sm[g];
    int run = base;
    for (int b = 0; b < NB_A; ++b) {
        off2[b * GG + g] = run;
        run += hist[b * GG + g];
    }
}

__global__ __launch_bounds__(256) void k_a3(const int* __restrict__ src,
                                            const int* __restrict__ dst,
                                            const int* __restrict__ off2,
                                            uint* __restrict__ gpack) {
    __shared__ int cur[GG];
    int tid = threadIdx.x;
    cur[tid] = off2[blockIdx.x * GG + tid];
    cur[tid + 256] = off2[blockIdx.x * GG + tid + 256];
    __syncthreads();
    int base = blockIdx.x * ECH_A;
#pragma unroll
    for (int it = 0; it < ECH_A / 256; ++it) {
        int e = base + it * 256 + tid;
        int s = src[e], d = dst[e];
        int g = s / NPG;
        int pos = atomicAdd(&cur[g], 1);
        gpack[pos] = ((uint)(s - g * NPG) << 8) | (uint)(d - g * NPG);
    }
}

// B: per-graph in-LDS sort by dst + COALESCED padded slot-table emit + overflow +
//    wgt emit + FUSED layer-1 (2-wide agg + transform + LN). Zero global atomics.
__global__ __launch_bounds__(256) void k_bsort(
    const float* __restrict__ x, const int* __restrict__ goff,
    const uint* __restrict__ gpack, const float* __restrict__ W1,
    const float* __restrict__ gb1, const float* __restrict__ lng,
    const float* __restrict__ lnb, uint2* __restrict__ slots,
    uint2* __restrict__ ovf, int* __restrict__ ovfcnt,
    float* __restrict__ wgtv, float* __restrict__ hout) {
    int g = ((blockIdx.x & 7) << 6) | (blockIdx.x >> 3);  // XCD-local graphs
    __shared__ float2 xs[NPG];
    __shared__ float2 aggl[NPG];
    __shared__ int cnt2[NPG];
    __shared__ int lnoff[NPG + 1];
    __shared__ int cur[NPG];
    __shared__ float rsq[NPG];
    __shared__ float cwl[NPG];
    __shared__ uint srec[SCAP];
    __shared__ int sm[256];
    __shared__ uint2 ovfl[128];
    __shared__ int ovfcur;
    int tid = threadIdx.x;
    int base = goff[g], E = goff[g + 1] - base;
    const float2* x2 = (const float2*)x;
    if (tid < NPG) { xs[tid] = x2[g * NPG + tid]; cnt2[tid] = 0; cwl[tid] = 0.f; }
    if (tid == 0) ovfcur = 0;
    __syncthreads();
    for (int i = tid; i < E; i += 256) atomicAdd(&cnt2[gpack[base + i] & 255u], 1);
    __syncthreads();
    int c = (tid < NPG) ? cnt2[tid] : 0;
    sm[tid] = c;
    __syncthreads();
    for (int d = 1; d < 256; d <<= 1) {
        int v = (tid >= d) ? sm[tid - d] : 0;
        __syncthreads();
        sm[tid] += v;
        __syncthreads();
    }
    if (tid < NPG) {
        lnoff[tid] = sm[tid] - c;
        cur[tid] = sm[tid] - c;
        rsq[tid] = rsqrtf((float)(c + 1));
    }
    if (tid == 0) lnoff[NPG] = E;
    __syncthreads();
    for (int i = tid; i < E; i += 256) {
        uint r = gpack[base + i];
        int pos = atomicAdd(&cur[r & 255u], 1);
        srec[pos] = r;
    }
    __syncthreads();
    // column sums for pooled-readout weights
    for (int i = tid; i < E; i += 256) {
        uint r = srec[i];
        atomicAdd(&cwl[r >> 8], rsq[r >> 8] * rsq[r & 255u]);
    }
    __syncthreads();
    // coalesced padded slot emit (consecutive addresses per lane)
    {
        uint2* sbase = &slots[(size_t)g * NPG * NSLOT];
        for (int li = tid; li < NPG * NSLOT; li += 256) {
            int n = li >> 4, s = li & 15;
            int e0 = lnoff[n];
            int En = lnoff[n + 1] - e0;
            float rd = rsq[n];
            uint2 v;
            if (s == 0) {
                v = make_uint2((uint)(g * NPG + n), __float_as_uint(rd * rd));
            } else if (s - 1 < En) {
                uint r = srec[e0 + s - 1];
                int ls = (int)(r >> 8);
                v = make_uint2((uint)(g * NPG + ls), __float_as_uint(rsq[ls] * rd));
            } else {
                v = make_uint2((uint)(g * NPG + n), 0u);
            }
            sbase[li] = v;
        }
    }
    // per-node: 2-wide x aggregation over full CSR + overflow records + wgt
    if (tid < NPG) {
        float rd = rsq[tid];
        float dv = rd * rd;  // 1/deg
        float ax = xs[tid].x * dv, ay = xs[tid].y * dv;
        int e0 = lnoff[tid], e1 = lnoff[tid + 1];
        for (int e = e0; e < e1; ++e) {
            uint r = srec[e];
            int ls = (int)(r >> 8);
            float w = rsq[ls] * rd;
            ax += xs[ls].x * w;
            ay += xs[ls].y * w;
        }
        for (int e = e0 + NSLOT - 1; e < e1; ++e) {  // rare overflow (deg > 15)
            uint r = srec[e];
            int ls = (int)(r >> 8);
            int p = atomicAdd(&ovfcur, 1);
            if (p < 128)
                ovfl[p] = make_uint2(((uint)tid << 17) | (uint)(g * NPG + ls),
                                     __float_as_uint(rsq[ls] * rd));
        }
        aggl[tid] = make_float2(ax, ay);
        wgtv[g * NPG + tid] = cwl[tid] + dv;
    }
    __syncthreads();
    int nov = ovfcur < 128 ? ovfcur : 128;
    if (tid == 0) ovfcnt[g] = nov;
    if (tid < nov) ovf[g * 128 + tid] = ovfl[tid];
    // fused layer 1: transform + bias/relu/LN
    int lane = tid & 63, wid = tid >> 6;
    float w0 = W1[lane], w1 = W1[64 + lane];
    float gbj = gb1[lane], lgj = lng[lane], lbj = lnb[lane];
    for (int i = wid; i < NPG; i += 4) {
        float2 a = aggl[i];
        float u = fmaxf(a.x * w0 + a.y * w1 + gbj, 0.f);
        float s2 = u, q2 = u * u;
        wave_sum64_2(s2, q2);
        float mean = s2 * (1.f / 64.f);
        float var = q2 * (1.f / 64.f) - mean * mean;
        hout[(size_t)(g * NPG + i) * 64 + lane] = (u - mean) * rsqrtf(var + 1e-5f) * lgj + lbj;
    }
}

// ---------------- GCN layer 2: static slot gather + W2 + LN (25-node chunks) -------

__global__ __launch_bounds__(256, 4) void k_agg_lin_ln(
    const float* __restrict__ t, const float* __restrict__ W,
    const float* __restrict__ gb, const float* __restrict__ lng,
    const float* __restrict__ lnb, const uint2* __restrict__ slots,
    const uint2* __restrict__ ovf, const int* __restrict__ ovfcnt,
    float* __restrict__ hout) {
    int c = ((blockIdx.x & 7) << 9) | (blockIdx.x >> 3);  // 4096 chunks, XCD-local
    int n0 = c * CHK;
    int g = c >> 3, lbase = (c & 7) * CHK;
    __shared__ float hs[CHK][64];
    __shared__ uint2 slt[CHK][NSLOT];
    int tid = threadIdx.x, lane = tid & 63, wid = tid >> 6;
    int grp = lane >> 4, fq = lane & 15;
    {   // stage slot table (coalesced)
        const float4* s4 = (const float4*)&slots[(size_t)n0 * NSLOT];
        float4* d4 = (float4*)slt;
        for (int i = tid; i < CHK * NSLOT / 2; i += 256) d4[i] = s4[i];
    }
    __syncthreads();
    for (int i = wid; i < CHK; i += 4) {
        float4 acc = make_float4(0.f, 0.f, 0.f, 0.f);
#pragma unroll
        for (int r = 0; r < 4; ++r) {            // fully static: 16 slots
            uint2 s = slt[i][r * 4 + grp];
            float w = __uint_as_float(s.y);
            float4 tv = *(const float4*)&t[(size_t)s.x * 64 + fq * 4];
            acc.x += tv.x * w; acc.y += tv.y * w;
            acc.z += tv.z * w; acc.w += tv.w * w;
        }
        acc.x += __shfl_xor(acc.x, 16); acc.y += __shfl_xor(acc.y, 16);
        acc.z += __shfl_xor(acc.z, 16); acc.w += __shfl_xor(acc.w, 16);
        acc.x += __shfl_xor(acc.x, 32); acc.y += __shfl_xor(acc.y, 32);
        acc.z += __shfl_xor(acc.z, 32); acc.w += __shfl_xor(acc.w, 32);
        if (grp == 0) *(float4*)&hs[i][fq * 4] = acc;
    }
    __syncthreads();
    int nov = ovfcnt[g];
    if (nov && wid == 0) {  // rare overflow edges
        for (int k = 0; k < nov; ++k) {
            uint2 r = ovf[g * 128 + k];
            int ld = r.x >> 17;
            if (ld >= lbase && ld < lbase + CHK)
                hs[ld - lbase][lane] +=
                    t[(size_t)(r.x & 0x1FFFFu) * 64 + lane] * __uint_as_float(r.y);
        }
    }
    __syncthreads();
    float wreg[64];
#pragma unroll
    for (int k = 0; k < 64; ++k) wreg[k] = W[k * 64 + lane];
    float gbj = gb[lane], lgj = lng[lane], lbj = lnb[lane];
    for (int i = wid; i < CHK; i += 4) {
        const float4* hrow = (const float4*)&hs[i][0];
        float a0 = 0.f, a1 = 0.f;
#pragma unroll
        for (int k4 = 0; k4 < 16; k4 += 2) {
            float4 h0 = hrow[k4], h1 = hrow[k4 + 1];
            a0 += h0.x * wreg[4 * k4] + h0.y * wreg[4 * k4 + 1] +
                  h0.z * wreg[4 * k4 + 2] + h0.w * wreg[4 * k4 + 3];
            a1 += h1.x * wreg[4 * k4 + 4] + h1.y * wreg[4 * k4 + 5] +
                  h1.z * wreg[4 * k4 + 6] + h1.w * wreg[4 * k4 + 7];
        }
        float u = fmaxf(a0 + a1 + gbj, 0.f);
        float s = u, q = u * u;
        wave_sum64_2(s, q);
        float mean = s * (1.f / 64.f);
        float var = q * (1.f / 64.f) - mean * mean;
        hout[(size_t)(n0 + i) * 64 + lane] = (u - mean) * rsqrtf(var + 1e-5f) * lgj + lbj;
    }
}

// layer 3 + readout + 64->128 transform + PE, fused; float4-vectorized h2 read
__global__ __launch_bounds__(256) void k_wpool_emb(
    const float* __restrict__ h2, const float* __restrict__ wgtv,
    const float* __restrict__ W3, const float* __restrict__ b3,
    float* __restrict__ seq) {
    int g = ((blockIdx.x & 7) << 6) | (blockIdx.x >> 3);
    int n0 = g * NPG;
    __shared__ float wgt[NPG];
    __shared__ float red[16][64];
    __shared__ float ps[64];
    int tid = threadIdx.x, lane = tid & 63, w = tid >> 6;
    int grp = lane >> 4, fq = lane & 15;
    for (int i = tid; i < NPG; i += 256) wgt[i] = wgtv[n0 + i];
    __syncthreads();
    float4 acc = make_float4(0.f, 0.f, 0.f, 0.f);
    for (int row = w * 4 + grp; row < NPG; row += 16) {
        float4 v = *(const float4*)&h2[(size_t)(n0 + row) * 64 + fq * 4];
        float wg = wgt[row];
        acc.x += v.x * wg; acc.y += v.y * wg; acc.z += v.z * wg; acc.w += v.w * wg;
    }
    *(float4*)&red[w * 4 + grp][fq * 4] = acc;
    __syncthreads();
    if (tid < 64) {
        float s = 0.f;
#pragma unroll
        for (int k = 0; k < 16; ++k) s += red[k][tid];
        ps[tid] = s * (1.f / NPG);
    }
    __syncthreads();
    if (tid < 128) {
        int d = tid;
        float a = b3[d];
#pragma unroll 8
        for (int k = 0; k < 64; ++k) a += ps[k] * W3[k * DD + d];
        float freq = expf((float)(d & ~1) * (-9.210340371976184f / 128.f));
        float ang = (float)(g & (TT - 1)) * freq;
        a += (d & 1) ? cosf(ang) : sinf(ang);
        seq[(size_t)g * DD + d] = a;
    }
}

// ---------------- Transformer: 2 fused kernels per layer ----------------

// qkv (one head) + attention, per (batch, head) block, 512 threads
__global__ __launch_bounds__(512) void k_qkv_attn(
    const float* __restrict__ seq, const float* __restrict__ Wqkv,
    const float* __restrict__ bqkv, float* __restrict__ abuf) {
    int b = blockIdx.x >> 2, h = blockIdx.x & 3;
    __shared__ float seqs[64][132];             // pad 132: b128 conflict-free
    __shared__ float Qs[64][36], Ks[64][36], Vs[64][36];
    __shared__ float Ss[64][68];
    int tid = threadIdx.x;
    for (int i = tid; i < 64 * 32; i += 512) {
        int r = i >> 5, c = i & 31;
        float4 v = *(const float4*)&seq[(size_t)(b * 64 + r) * DD + c * 4];
        *(float4*)&seqs[r][c * 4] = v;
    }
    __syncthreads();
    // qkv: 96 outputs (q0-31,k0-31,v0-31), 8 j-groups x 12, rows wave-uniform
    {
        int r = tid & 63, jg = tid >> 6;
        float acc[12];
        int wrow[12];
#pragma unroll
        for (int i = 0; i < 12; ++i) {
            int jj = jg * 12 + i;
            int row = (jj < 32) ? (h * 32 + jj)
                    : (jj < 64) ? (128 + h * 32 + jj - 32)
                                : (256 + h * 32 + jj - 64);
            wrow[i] = row;
            acc[i] = bqkv[row];
        }
        for (int kc = 0; kc < 8; ++kc) {
            float4 s0 = *(const float4*)&seqs[r][kc * 16 + 0];
            float4 s1 = *(const float4*)&seqs[r][kc * 16 + 4];
            float4 s2 = *(const float4*)&seqs[r][kc * 16 + 8];
            float4 s3 = *(const float4*)&seqs[r][kc * 16 + 12];
#pragma unroll
            for (int i = 0; i < 12; ++i) {
                const float4* wp = (const float4*)&Wqkv[(size_t)wrow[i] * DD + kc * 16];
                float4 w0 = wp[0], w1 = wp[1], w2 = wp[2], w3 = wp[3];
                acc[i] += s0.x * w0.x + s0.y * w0.y + s0.z * w0.z + s0.w * w0.w +
                          s1.x * w1.x + s1.y * w1.y + s1.z * w1.z + s1.w * w1.w +
                          s2.x * w2.x + s2.y * w2.y + s2.z * w2.z + s2.w * w2.w +
                          s3.x * w3.x + s3.y * w3.y + s3.z * w3.z + s3.w * w3.w;
            }
        }
#pragma unroll
        for (int i = 0; i < 12; ++i) {
            int jj = jg * 12 + i;
            if (jj < 32) Qs[r][jj] = acc[i];
            else if (jj < 64) Ks[r][jj - 32] = acc[i];
            else Vs[r][jj - 64] = acc[i];
        }
    }
    __syncthreads();
    // attention: 8 lanes per query
    int q = tid >> 3, kg = tid & 7;
    const float scale = 0.17677669529663687f;  // 1/sqrt(32)
    float p[8];
    float mx = -1e30f;
#pragma unroll
    for (int kk = 0; kk < 8; ++kk) {
        int k = kg * 8 + kk;
        float a = 0.f;
#pragma unroll
        for (int dq = 0; dq < 8; ++dq) {
            float4 qv = *(const float4*)&Qs[q][dq * 4];
            float4 kv = *(const float4*)&Ks[k][dq * 4];
            a += qv.x * kv.x + qv.y * kv.y + qv.z * kv.z + qv.w * kv.w;
        }
        p[kk] = a * scale;
        mx = fmaxf(mx, p[kk]);
    }
    mx = fmaxf(mx, __shfl_xor(mx, 1));
    mx = fmaxf(mx, __shfl_xor(mx, 2));
    mx = fmaxf(mx, __shfl_xor(mx, 4));
    float ssum = 0.f;
#pragma unroll
    for (int kk = 0; kk < 8; ++kk) {
        p[kk] = expf(p[kk] - mx);
        ssum += p[kk];
    }
    ssum += __shfl_xor(ssum, 1);
    ssum += __shfl_xor(ssum, 2);
    ssum += __shfl_xor(ssum, 4);
    float inv = 1.f / ssum;
#pragma unroll
    for (int kk = 0; kk < 8; ++kk) Ss[q][kg * 8 + kk] = p[kk] * inv;
    __syncthreads();
    float4 o = make_float4(0.f, 0.f, 0.f, 0.f);
    for (int k = 0; k < 64; ++k) {
        float pw = Ss[q][k];
        float4 v = *(const float4*)&Vs[k][kg * 4];
        o.x += pw * v.x; o.y += pw * v.y; o.z += pw * v.z; o.w += pw * v.w;
    }
    *(float4*)&abuf[(size_t)(b * 64 + q) * DD + h * 32 + kg * 4] = o;
}

// proj + LN + ffn1 + relu + ffn2 + residual + LN — fully row-local, 2 rows/block
__global__ __launch_bounds__(256) void k_post(
    const float* __restrict__ abuf, const float* __restrict__ Wo,
    const float* __restrict__ bo, const float* __restrict__ g1,
    const float* __restrict__ bl1, const float* __restrict__ Wf1,
    const float* __restrict__ bf1, const float* __restrict__ Wf2,
    const float* __restrict__ bf2, const float* __restrict__ g2,
    const float* __restrict__ bl2, float* __restrict__ seq) {
    int m0 = blockIdx.x * 2, tid = threadIdx.x;
    __shared__ float arow[2][128];
    __shared__ float srow[2][128];
    __shared__ float f1[2][512];
    __shared__ float pf[2][128];
    __shared__ float sred[4][2];
    __shared__ float sred2[2][4];
    int rr = tid >> 7, d0 = tid & 127;
    arow[rr][d0] = abuf[(size_t)(m0 + rr) * DD + d0];
    __syncthreads();
    // ---- proj + residual + LN -> srow ----
    {
        float acc = bo[d0];
        const float4* wr = (const float4*)&Wo[(size_t)d0 * DD];
        const float4* ar = (const float4*)arow[rr];
#pragma unroll
        for (int k = 0; k < 32; ++k) {
            float4 w = wr[k], a = ar[k];
            acc += a.x * w.x + a.y * w.y + a.z * w.z + a.w * w.w;
        }
        float u = seq[(size_t)(m0 + rr) * DD + d0] + acc;
        float s = u, q = u * u;
        wave_sum64_2(s, q);
        int wv = tid >> 6;
        if ((tid & 63) == 0) { sred[wv][0] = s; sred[wv][1] = q; }
        __syncthreads();
        int wp = rr * 2;
        s = sred[wp][0] + sred[wp + 1][0];
        q = sred[wp][1] + sred[wp + 1][1];
        float mean = s * (1.f / 128.f);
        float var = q * (1.f / 128.f) - mean * mean;
        float rstd = rsqrtf(var + 1e-5f);
        srow[rr][d0] = (u - mean) * rstd * g1[d0] + bl1[d0];
    }
    __syncthreads();
    // ---- ffn1 + relu (512 outputs x 2 rows; W row reused across rows) ----
    const float4* s0 = (const float4*)srow[0];
    const float4* s1 = (const float4*)srow[1];
#pragma unroll
    for (int rep = 0; rep < 2; ++rep) {
        int o = tid + rep * 256;
        float bv = bf1[o];
        float a0 = bv, a1 = bv;
        const float4* wr = (const float4*)&Wf1[(size_t)o * DD];
#pragma unroll
        for (int k = 0; k < 32; ++k) {
            float4 w = wr[k];
            float4 x0 = s0[k], x1 = s1[k];
            a0 += x0.x * w.x + x0.y * w.y + x0.z * w.z + x0.w * w.w;
            a1 += x1.x * w.x + x1.y * w.y + x1.z * w.z + x1.w * w.w;
        }
        f1[0][o] = fmaxf(a0, 0.f);
        f1[1][o] = fmaxf(a1, 0.f);
    }
    __syncthreads();
    // ---- ffn2 (half-split K) + residual + LN ----
    int d = tid & 127, half = tid >> 7;
    float b0 = half ? 0.f : bf2[d];
    float a0 = b0, a1 = b0;
    const float4* wr2 = (const float4*)&Wf2[(size_t)d * 512 + half * 256];
    const float4* f10 = (const float4*)&f1[0][half * 256];
    const float4* f11 = (const float4*)&f1[1][half * 256];
#pragma unroll
    for (int k = 0; k < 64; ++k) {
        float4 w = wr2[k];
        float4 x0 = f10[k], x1 = f11[k];
        a0 += x0.x * w.x + x0.y * w.y + x0.z * w.z + x0.w * w.w;
        a1 += x1.x * w.x + x1.y * w.y + x1.z * w.z + x1.w * w.w;
    }
    if (half) { pf[0][d] = a0; pf[1][d] = a1; }
    __syncthreads();
    if (half == 0) {
        float u0 = srow[0][d] + a0 + pf[0][d];
        float u1 = srow[1][d] + a1 + pf[1][d];
        float s0_ = u0, q0_ = u0 * u0, s1_ = u1, q1_ = u1 * u1;
        wave_sum64_2(s0_, q0_);
        wave_sum64_2(s1_, q1_);
        int w_ = d >> 6;
        if ((d & 63) == 0) {
            sred2[w_][0] = s0_; sred2[w_][1] = q0_;
            sred2[w_][2] = s1_; sred2[w_][3] = q1_;
        }
        __syncthreads();
        float S0 = sred2[0][0] + sred2[1][0], Q0 = sred2[0][1] + sred2[1][1];
        float S1 = sred2[0][2] + sred2[1][2], Q1 = sred2[0][3] + sred2[1][3];
        float mean0 = S0 * (1.f / 128.f);
        float var0 = Q0 * (1.f / 128.f) - mean0 * mean0;
        float rstd0 = rsqrtf(var0 + 1e-5f);
        float mean1 = S1 * (1.f / 128.f);
        float var1 = Q1 * (1.f / 128.f) - mean1 * mean1;
        float rstd1 = rsqrtf(var1 + 1e-5f);
        seq[(size_t)m0 * DD + d] = (u0 - mean0) * rstd0 * g2[d] + bl2[d];
        seq[(size_t)(m0 + 1) * DD + d] = (u1 - mean1) * rstd1 * g2[d] + bl2[d];
    } else {
        __syncthreads();
    }
}

__global__ __launch_bounds__(128) void k_head(
    const float* __restrict__ seq, const float* __restrict__ W1,
    const float* __restrict__ b1, const float* __restrict__ W2,
    const float* __restrict__ b2, float* __restrict__ out) {
    int b = blockIdx.x, t = threadIdx.x;
    __shared__ float pooled[DD];
    __shared__ float hid[64];
    float s = 0.f;
    for (int i = 0; i < TT; ++i) s += seq[(size_t)(b * TT + i) * DD + t];
    pooled[t] = s * (1.f / TT);
    __syncthreads();
    if (t < 64) {
        float a = b1[t];
        const float* wr = W1 + t * DD;
        for (int k = 0; k < DD; ++k) a += pooled[k] * wr[k];
        hid[t] = fmaxf(a, 0.f);
    }
    __syncthreads();
    if (t < 2) {
        float a = b2[t];
        const float* wr = W2 + t * 64;
        for (int k = 0; k < 64; ++k) a += hid[k] * wr[k];
        out[b * 2 + t] = a;
    }
}

// ---------------- host ----------------

extern "C" void kernel_launch(void* const* d_in, const int* in_sizes, int n_in,
                              void* d_out, int out_size, void* d_ws, size_t ws_size,
                              hipStream_t stream) {
    const float* x     = (const float*)d_in[0];
    const int*   esrc  = (const int*)d_in[1];
    const int*   edst  = (const int*)d_in[2];
    const float* gW1   = (const float*)d_in[4];
    const float* gb1   = (const float*)d_in[5];
    const float* ln1g  = (const float*)d_in[6];
    const float* ln1b  = (const float*)d_in[7];
    const float* gW2   = (const float*)d_in[8];
    const float* gb2   = (const float*)d_in[9];
    const float* ln2g  = (const float*)d_in[10];
    const float* ln2b  = (const float*)d_in[11];
    const float* gW3   = (const float*)d_in[12];
    const float* gb3   = (const float*)d_in[13];
    const float* tWqkv = (const float*)d_in[14];
    const float* tbqkv = (const float*)d_in[15];
    const float* tWo   = (const float*)d_in[16];
    const float* tbo   = (const float*)d_in[17];
    const float* tg1   = (const float*)d_in[18];
    const float* tb1   = (const float*)d_in[19];
    const float* tg2   = (const float*)d_in[20];
    const float* tb2   = (const float*)d_in[21];
    const float* tWf1  = (const float*)d_in[22];
    const float* tbf1  = (const float*)d_in[23];
    const float* tWf2  = (const float*)d_in[24];
    const float* tbf2  = (const float*)d_in[25];
    const float* hW1   = (const float*)d_in[26];
    const float* hb1   = (const float*)d_in[27];
    const float* hW2   = (const float*)d_in[28];
    const float* hb2   = (const float*)d_in[29];
    float* out = (float*)d_out;

    int*   hist   = (int*)d_ws;                 // NB_A*512
    int*   off2   = hist + NB_A * GG;           // NB_A*512
    int*   goff   = off2 + NB_A * GG;           // 516
    uint*  gpack  = (uint*)(goff + 516);        // EE
    uint2* slots  = (uint2*)(gpack + EE);       // NN*16 (16B-aligned)
    uint2* ovf    = slots + (size_t)NN * NSLOT; // GG*128
    int*   ovfcnt = (int*)(ovf + GG * 128);     // GG
    float* wgtv   = (float*)(ovfcnt + GG);      // NN
    float* bufA = wgtv + NN;                    // NN*64 (h1)
    float* bufB = bufA + (size_t)NN * 64;       // NN*64 (h2)
    float* seq  = bufB + (size_t)NN * 64;       // 512*128
    float* abuf = seq + GG * DD;                // 512*128

    // CSR build (no global atomics) + fused layer 1
    k_a1<<<NB_A, 256, 0, stream>>>(esrc, hist);
    k_a2<<<1, 512, 0, stream>>>(hist, off2, goff);
    k_a3<<<NB_A, 256, 0, stream>>>(esrc, edst, off2, gpack);
    k_bsort<<<GG, 256, 0, stream>>>(x, goff, gpack, gW1, gb1, ln1g, ln1b,
                                    slots, ovf, ovfcnt, wgtv, bufA);

    // GCN layer 2 + pooled readout
    k_agg_lin_ln<<<NN / CHK, 256, 0, stream>>>(bufA, gW2, gb2, ln2g, ln2b,
                                               slots, ovf, ovfcnt, bufB);
    k_wpool_emb<<<GG, 256, 0, stream>>>(bufB, wgtv, gW3, gb3, seq);

    // Transformer: 2 kernels per layer
    for (int l = 0; l < LL; l++) {
        k_qkv_attn<<<BB * 4, 512, 0, stream>>>(
            seq, tWqkv + (size_t)l * 384 * 128, tbqkv + l * 384, abuf);
        k_post<<<GG / 2, 256, 0, stream>>>(
            abuf, tWo + (size_t)l * 128 * 128, tbo + l * 128,
            tg1 + l * 128, tb1 + l * 128,
            tWf1 + (size_t)l * 512 * 128, tbf1 + l * 512,
            tWf2 + (size_t)l * 128 * 512, tbf2 + l * 128,
            tg2 + l * 128, tb2 + l * 128, seq);
    }

    // head
    k_head<<<BB, DD, 0, stream>>>(seq, hW1, hb1, hW2, hb2, out);
}

// Round 17
// 368.598 us; speedup vs baseline: 1.0458x; 1.0458x over previous
//
#include <hip/hip_runtime.h>

#define NN   102400
#define EE   819200
#define GG   512
#define NPG  200
#define DD   128
#define TT   64
#define BB   8
#define LL   4
#define NB_A   320     // CSR-build blocks
#define ECH_A  2560    // edges per CSR-build block (EE / NB_A)
#define SCAP 2560      // per-graph sorted-edge LDS capacity
#define NSLOT 16       // slot 0 = self, 1..15 edges, overflow list beyond
#define CHK  50        // nodes per agg chunk (4 per graph)

typedef unsigned int uint;

static __device__ __forceinline__ void wave_sum64_2(float& a, float& b) {
#pragma unroll
    for (int off = 32; off > 0; off >>= 1) {
        a += __shfl_xor(a, off, 64);
        b += __shfl_xor(b, off, 64);
    }
}

// ---------------- CSR build: coalesced two-level counting sort ----------------

__global__ __launch_bounds__(256) void k_a1(const int* __restrict__ src,
                                            int* __restrict__ hist) {
    __shared__ int h[GG];
    int tid = threadIdx.x;
    h[tid] = 0; h[tid + 256] = 0;
    __syncthreads();
    int base = blockIdx.x * ECH_A;
#pragma unroll
    for (int it = 0; it < ECH_A / 256; ++it)
        atomicAdd(&h[src[base + it * 256 + tid] / NPG], 1);
    __syncthreads();
    hist[blockIdx.x * GG + tid] = h[tid];
    hist[blockIdx.x * GG + tid + 256] = h[tid + 256];
}

// a2a: per-graph totals (one wave per graph)
__global__ __launch_bounds__(64) void k_a2a(const int* __restrict__ hist,
                                            int* __restrict__ gcnt) {
    int g = blockIdx.x, lane = threadIdx.x;
    int s = 0;
#pragma unroll
    for (int i = 0; i < NB_A / 64; ++i) s += hist[(i * 64 + lane) * GG + g];
#pragma unroll
    for (int off = 32; off > 0; off >>= 1) s += __shfl_xor(s, off, 64);
    if (lane == 0) gcnt[g] = s;
}

// a2b: prefix scan of 512 graph totals
__global__ __launch_bounds__(512) void k_a2b(const int* __restrict__ gcnt,
                                             int* __restrict__ goff) {
    __shared__ int sm[GG];
    int g = threadIdx.x;
    int c = gcnt[g];
    sm[g] = c;
    __syncthreads();
    for (int d = 1; d < GG; d <<= 1) {
        int v = (g >= d) ? sm[g - d] : 0;
        __syncthreads();
        sm[g] += v;
        __syncthreads();
    }
    goff[g] = sm[g] - c;
    if (g == GG - 1) goff[GG] = sm[g];
}

// a2c: per-(block,graph) cursors via wave-scan (one wave per graph)
__global__ __launch_bounds__(512) void k_a2c(const int* __restrict__ hist,
                                             const int* __restrict__ goff,
                                             int* __restrict__ off2) {
    int g = blockIdx.x * 8 + (threadIdx.x >> 6);
    int lane = threadIdx.x & 63;
    int running = goff[g];
#pragma unroll
    for (int cchunk = 0; cchunk < NB_A / 64; ++cchunk) {
        int b = cchunk * 64 + lane;
        int v = hist[b * GG + g];
        int s = v;
#pragma unroll
        for (int off = 1; off < 64; off <<= 1) {
            int t_ = __shfl_up(s, off, 64);
            if (lane >= off) s += t_;
        }
        off2[b * GG + g] = running + s - v;
        running += __shfl(s, 63, 64);
    }
}

__global__ __launch_bounds__(256) void k_a3(const int* __restrict__ src,
                                            const int* __restrict__ dst,
                                            const int* __restrict__ off2,
                                            uint* __restrict__ gpack) {
    __shared__ int cur[GG];
    int tid = threadIdx.x;
    cur[tid] = off2[blockIdx.x * GG + tid];
    cur[tid + 256] = off2[blockIdx.x * GG + tid + 256];
    __syncthreads();
    int base = blockIdx.x * ECH_A;
#pragma unroll
    for (int it = 0; it < ECH_A / 256; ++it) {
        int e = base + it * 256 + tid;
        int s = src[e], d = dst[e];
        int g = s / NPG;
        int pos = atomicAdd(&cur[g], 1);
        gpack[pos] = ((uint)(s - g * NPG) << 8) | (uint)(d - g * NPG);
    }
}

// B: per-graph in-LDS sort by dst + COALESCED padded slot-table emit + overflow +
//    wgt emit + FUSED layer-1 (2-wide agg + transform + LN). Zero global atomics.
__global__ __launch_bounds__(256) void k_bsort(
    const float* __restrict__ x, const int* __restrict__ goff,
    const uint* __restrict__ gpack, const float* __restrict__ W1,
    const float* __restrict__ gb1, const float* __restrict__ lng,
    const float* __restrict__ lnb, uint2* __restrict__ slots,
    uint2* __restrict__ ovf, int* __restrict__ ovfcnt,
    float* __restrict__ wgtv, float* __restrict__ hout) {
    int g = ((blockIdx.x & 7) << 6) | (blockIdx.x >> 3);  // XCD-local graphs
    __shared__ float2 xs[NPG];
    __shared__ float2 aggl[NPG];
    __shared__ int cnt2[NPG];
    __shared__ int lnoff[NPG + 1];
    __shared__ int cur[NPG];
    __shared__ float rsq[NPG];
    __shared__ float cwl[NPG];
    __shared__ uint srec[SCAP];
    __shared__ int sm[256];
    __shared__ uint2 ovfl[128];
    __shared__ int ovfcur;
    int tid = threadIdx.x;
    int base = goff[g], E = goff[g + 1] - base;
    const float2* x2 = (const float2*)x;
    if (tid < NPG) { xs[tid] = x2[g * NPG + tid]; cnt2[tid] = 0; cwl[tid] = 0.f; }
    if (tid == 0) ovfcur = 0;
    __syncthreads();
    for (int i = tid; i < E; i += 256) atomicAdd(&cnt2[gpack[base + i] & 255u], 1);
    __syncthreads();
    int c = (tid < NPG) ? cnt2[tid] : 0;
    sm[tid] = c;
    __syncthreads();
    for (int d = 1; d < 256; d <<= 1) {
        int v = (tid >= d) ? sm[tid - d] : 0;
        __syncthreads();
        sm[tid] += v;
        __syncthreads();
    }
    if (tid < NPG) {
        lnoff[tid] = sm[tid] - c;
        cur[tid] = sm[tid] - c;
        rsq[tid] = rsqrtf((float)(c + 1));
    }
    if (tid == 0) lnoff[NPG] = E;
    __syncthreads();
    for (int i = tid; i < E; i += 256) {
        uint r = gpack[base + i];
        int pos = atomicAdd(&cur[r & 255u], 1);
        srec[pos] = r;
    }
    __syncthreads();
    // column sums for pooled-readout weights
    for (int i = tid; i < E; i += 256) {
        uint r = srec[i];
        atomicAdd(&cwl[r >> 8], rsq[r >> 8] * rsq[r & 255u]);
    }
    __syncthreads();
    // coalesced padded slot emit (consecutive addresses per lane)
    {
        uint2* sbase = &slots[(size_t)g * NPG * NSLOT];
        for (int li = tid; li < NPG * NSLOT; li += 256) {
            int n = li >> 4, s = li & 15;
            int e0 = lnoff[n];
            int En = lnoff[n + 1] - e0;
            float rd = rsq[n];
            uint2 v;
            if (s == 0) {
                v = make_uint2((uint)(g * NPG + n), __float_as_uint(rd * rd));
            } else if (s - 1 < En) {
                uint r = srec[e0 + s - 1];
                int ls = (int)(r >> 8);
                v = make_uint2((uint)(g * NPG + ls), __float_as_uint(rsq[ls] * rd));
            } else {
                v = make_uint2((uint)(g * NPG + n), 0u);
            }
            sbase[li] = v;
        }
    }
    // per-node: 2-wide x aggregation over full CSR + overflow records + wgt
    if (tid < NPG) {
        float rd = rsq[tid];
        float dv = rd * rd;  // 1/deg
        float ax = xs[tid].x * dv, ay = xs[tid].y * dv;
        int e0 = lnoff[tid], e1 = lnoff[tid + 1];
        for (int e = e0; e < e1; ++e) {
            uint r = srec[e];
            int ls = (int)(r >> 8);
            float w = rsq[ls] * rd;
            ax += xs[ls].x * w;
            ay += xs[ls].y * w;
        }
        for (int e = e0 + NSLOT - 1; e < e1; ++e) {  // rare overflow (deg > 15)
            uint r = srec[e];
            int ls = (int)(r >> 8);
            int p = atomicAdd(&ovfcur, 1);
            if (p < 128)
                ovfl[p] = make_uint2(((uint)tid << 17) | (uint)(g * NPG + ls),
                                     __float_as_uint(rsq[ls] * rd));
        }
        aggl[tid] = make_float2(ax, ay);
        wgtv[g * NPG + tid] = cwl[tid] + dv;
    }
    __syncthreads();
    int nov = ovfcur < 128 ? ovfcur : 128;
    if (tid == 0) ovfcnt[g] = nov;
    if (tid < nov) ovf[g * 128 + tid] = ovfl[tid];
    // fused layer 1: transform + bias/relu/LN
    int lane = tid & 63, wid = tid >> 6;
    float w0 = W1[lane], w1 = W1[64 + lane];
    float gbj = gb1[lane], lgj = lng[lane], lbj = lnb[lane];
    for (int i = wid; i < NPG; i += 4) {
        float2 a = aggl[i];
        float u = fmaxf(a.x * w0 + a.y * w1 + gbj, 0.f);
        float s2 = u, q2 = u * u;
        wave_sum64_2(s2, q2);
        float mean = s2 * (1.f / 64.f);
        float var = q2 * (1.f / 64.f) - mean * mean;
        hout[(size_t)(g * NPG + i) * 64 + lane] = (u - mean) * rsqrtf(var + 1e-5f) * lgj + lbj;
    }
}

// ---------------- GCN layer 2 + pooled readout, fused ----------------
// h2 never touches global: LN'd rows are pooled in-block, one atomic per (g,lane).

__global__ __launch_bounds__(256) void k_agg_lin_pool(
    const float* __restrict__ t, const float* __restrict__ W,
    const float* __restrict__ gb, const float* __restrict__ lng,
    const float* __restrict__ lnb, const uint2* __restrict__ slots,
    const uint2* __restrict__ ovf, const int* __restrict__ ovfcnt,
    const float* __restrict__ wgtv, float* __restrict__ pooled) {
    int c = ((blockIdx.x & 7) << 8) | (blockIdx.x >> 3);
    int n0 = c * CHK;
    int g = c >> 2, lbase = (c & 3) * CHK;
    __shared__ float hs[CHK][64];
    __shared__ uint2 slt[CHK][NSLOT];
    __shared__ float wgt[CHK];
    __shared__ float red[4][64];
    int tid = threadIdx.x, lane = tid & 63, wid = tid >> 6;
    int grp = lane >> 4, fq = lane & 15;
    {   // stage slot table (coalesced)
        const float4* s4 = (const float4*)&slots[(size_t)n0 * NSLOT];
        float4* d4 = (float4*)slt;
        for (int i = tid; i < CHK * NSLOT / 2; i += 256) d4[i] = s4[i];
    }
    if (tid < CHK) wgt[tid] = wgtv[n0 + tid];
    __syncthreads();
    for (int i = wid; i < CHK; i += 4) {
        float4 acc = make_float4(0.f, 0.f, 0.f, 0.f);
#pragma unroll
        for (int r = 0; r < 4; ++r) {            // fully static: 16 slots
            uint2 s = slt[i][r * 4 + grp];
            float w = __uint_as_float(s.y);
            float4 tv = *(const float4*)&t[(size_t)s.x * 64 + fq * 4];
            acc.x += tv.x * w; acc.y += tv.y * w;
            acc.z += tv.z * w; acc.w += tv.w * w;
        }
        acc.x += __shfl_xor(acc.x, 16); acc.y += __shfl_xor(acc.y, 16);
        acc.z += __shfl_xor(acc.z, 16); acc.w += __shfl_xor(acc.w, 16);
        acc.x += __shfl_xor(acc.x, 32); acc.y += __shfl_xor(acc.y, 32);
        acc.z += __shfl_xor(acc.z, 32); acc.w += __shfl_xor(acc.w, 32);
        if (grp == 0) *(float4*)&hs[i][fq * 4] = acc;
    }
    __syncthreads();
    int nov = ovfcnt[g];
    if (nov && wid == 0) {  // rare overflow edges
        for (int k = 0; k < nov; ++k) {
            uint2 r = ovf[g * 128 + k];
            int ld = r.x >> 17;
            if (ld >= lbase && ld < lbase + CHK)
                hs[ld - lbase][lane] +=
                    t[(size_t)(r.x & 0x1FFFFu) * 64 + lane] * __uint_as_float(r.y);
        }
    }
    __syncthreads();
    float wreg[64];
#pragma unroll
    for (int k = 0; k < 64; ++k) wreg[k] = W[k * 64 + lane];
    float gbj = gb[lane], lgj = lng[lane], lbj = lnb[lane];
    float psum = 0.f;
    for (int i = wid; i < CHK; i += 4) {
        const float4* hrow = (const float4*)&hs[i][0];
        float a0 = 0.f, a1 = 0.f;
#pragma unroll
        for (int k4 = 0; k4 < 16; k4 += 2) {
            float4 h0 = hrow[k4], h1 = hrow[k4 + 1];
            a0 += h0.x * wreg[4 * k4] + h0.y * wreg[4 * k4 + 1] +
                  h0.z * wreg[4 * k4 + 2] + h0.w * wreg[4 * k4 + 3];
            a1 += h1.x * wreg[4 * k4 + 4] + h1.y * wreg[4 * k4 + 5] +
                  h1.z * wreg[4 * k4 + 6] + h1.w * wreg[4 * k4 + 7];
        }
        float u = fmaxf(a0 + a1 + gbj, 0.f);
        float s = u, q = u * u;
        wave_sum64_2(s, q);
        float mean = s * (1.f / 64.f);
        float var = q * (1.f / 64.f) - mean * mean;
        float h = (u - mean) * rsqrtf(var + 1e-5f) * lgj + lbj;
        psum += h * wgt[i];
    }
    red[wid][lane] = psum;
    __syncthreads();
    if (tid < 64)
        atomicAdd(&pooled[g * 64 + tid],
                  red[0][tid] + red[1][tid] + red[2][tid] + red[3][tid]);
}

// pooled(64) @ W3 -> 128 + b3 + PE -> seq[g][d]
__global__ __launch_bounds__(128) void k_emb(
    const float* __restrict__ pooled, const float* __restrict__ W3,
    const float* __restrict__ b3, float* __restrict__ seq) {
    int g = blockIdx.x, d = threadIdx.x;
    __shared__ float ps[64];
    if (d < 64) ps[d] = pooled[g * 64 + d] * (1.f / NPG);
    __syncthreads();
    float a = b3[d];
#pragma unroll 8
    for (int k = 0; k < 64; ++k) a += ps[k] * W3[k * DD + d];
    float freq = expf((float)(d & ~1) * (-9.210340371976184f / 128.f));
    float ang = (float)(g & (TT - 1)) * freq;
    a += (d & 1) ? cosf(ang) : sinf(ang);
    seq[(size_t)g * DD + d] = a;
}

// ---------------- Transformer: 2 fused kernels per layer ----------------

// qkv (one head) + attention, per (batch, head) block, 512 threads
__global__ __launch_bounds__(512) void k_qkv_attn(
    const float* __restrict__ seq, const float* __restrict__ Wqkv,
    const float* __restrict__ bqkv, float* __restrict__ abuf) {
    int b = blockIdx.x >> 2, h = blockIdx.x & 3;
    __shared__ float seqs[64][132];             // pad 132: b128 conflict-free
    __shared__ float Qs[64][36], Ks[64][36], Vs[64][36];
    __shared__ float Ss[64][68];
    int tid = threadIdx.x;
    for (int i = tid; i < 64 * 32; i += 512) {
        int r = i >> 5, c = i & 31;
        float4 v = *(const float4*)&seq[(size_t)(b * 64 + r) * DD + c * 4];
        *(float4*)&seqs[r][c * 4] = v;
    }
    __syncthreads();
    // qkv: 96 outputs (q0-31,k0-31,v0-31), 8 j-groups x 12, rows wave-uniform
    {
        int r = tid & 63, jg = tid >> 6;
        float acc[12];
        int wrow[12];
#pragma unroll
        for (int i = 0; i < 12; ++i) {
            int jj = jg * 12 + i;
            int row = (jj < 32) ? (h * 32 + jj)
                    : (jj < 64) ? (128 + h * 32 + jj - 32)
                                : (256 + h * 32 + jj - 64);
            wrow[i] = row;
            acc[i] = bqkv[row];
        }
        for (int kc = 0; kc < 8; ++kc) {
            float4 s0 = *(const float4*)&seqs[r][kc * 16 + 0];
            float4 s1 = *(const float4*)&seqs[r][kc * 16 + 4];
            float4 s2 = *(const float4*)&seqs[r][kc * 16 + 8];
            float4 s3 = *(const float4*)&seqs[r][kc * 16 + 12];
#pragma unroll
            for (int i = 0; i < 12; ++i) {
                const float4* wp = (const float4*)&Wqkv[(size_t)wrow[i] * DD + kc * 16];
                float4 w0 = wp[0], w1 = wp[1], w2 = wp[2], w3 = wp[3];
                acc[i] += s0.x * w0.x + s0.y * w0.y + s0.z * w0.z + s0.w * w0.w +
                          s1.x * w1.x + s1.y * w1.y + s1.z * w1.z + s1.w * w1.w +
                          s2.x * w2.x + s2.y * w2.y + s2.z * w2.z + s2.w * w2.w +
                          s3.x * w3.x + s3.y * w3.y + s3.z * w3.z + s3.w * w3.w;
            }
        }
#pragma unroll
        for (int i = 0; i < 12; ++i) {
            int jj = jg * 12 + i;
            if (jj < 32) Qs[r][jj] = acc[i];
            else if (jj < 64) Ks[r][jj - 32] = acc[i];
            else Vs[r][jj - 64] = acc[i];
        }
    }
    __syncthreads();
    // attention: 8 lanes per query
    int q = tid >> 3, kg = tid & 7;
    const float scale = 0.17677669529663687f;  // 1/sqrt(32)
    float p[8];
    float mx = -1e30f;
#pragma unroll
    for (int kk = 0; kk < 8; ++kk) {
        int k = kg * 8 + kk;
        float a = 0.f;
#pragma unroll
        for (int dq = 0; dq < 8; ++dq) {
            float4 qv = *(const float4*)&Qs[q][dq * 4];
            float4 kv = *(const float4*)&Ks[k][dq * 4];
            a += qv.x * kv.x + qv.y * kv.y + qv.z * kv.z + qv.w * kv.w;
        }
        p[kk] = a * scale;
        mx = fmaxf(mx, p[kk]);
    }
    mx = fmaxf(mx, __shfl_xor(mx, 1));
    mx = fmaxf(mx, __shfl_xor(mx, 2));
    mx = fmaxf(mx, __shfl_xor(mx, 4));
    float ssum = 0.f;
#pragma unroll
    for (int kk = 0; kk < 8; ++kk) {
        p[kk] = expf(p[kk] - mx);
        ssum += p[kk];
    }
    ssum += __shfl_xor(ssum, 1);
    ssum += __shfl_xor(ssum, 2);
    ssum += __shfl_xor(ssum, 4);
    float inv = 1.f / ssum;
#pragma unroll
    for (int kk = 0; kk < 8; ++kk) Ss[q][kg * 8 + kk] = p[kk] * inv;
    __syncthreads();
    float4 o = make_float4(0.f, 0.f, 0.f, 0.f);
    for (int k = 0; k < 64; ++k) {
        float pw = Ss[q][k];
        float4 v = *(const float4*)&Vs[k][kg * 4];
        o.x += pw * v.x; o.y += pw * v.y; o.z += pw * v.z; o.w += pw * v.w;
    }
    *(float4*)&abuf[(size_t)(b * 64 + q) * DD + h * 32 + kg * 4] = o;
}

// proj + LN + ffn1 + relu + ffn2 + residual + LN — fully row-local, 2 rows/block
__global__ __launch_bounds__(256) void k_post(
    const float* __restrict__ abuf, const float* __restrict__ Wo,
    const float* __restrict__ bo, const float* __restrict__ g1,
    const float* __restrict__ bl1, const float* __restrict__ Wf1,
    const float* __restrict__ bf1, const float* __restrict__ Wf2,
    const float* __restrict__ bf2, const float* __restrict__ g2,
    const float* __restrict__ bl2, float* __restrict__ seq) {
    int m0 = blockIdx.x * 2, tid = threadIdx.x;
    __shared__ float arow[2][128];
    __shared__ float srow[2][128];
    __shared__ float f1[2][512];
    __shared__ float pf[2][128];
    __shared__ float sred[4][2];
    __shared__ float sred2[2][4];
    int rr = tid >> 7, d0 = tid & 127;
    arow[rr][d0] = abuf[(size_t)(m0 + rr) * DD + d0];
    __syncthreads();
    // ---- proj + residual + LN -> srow ----
    {
        float acc = bo[d0];
        const float4* wr = (const float4*)&Wo[(size_t)d0 * DD];
        const float4* ar = (const float4*)arow[rr];
#pragma unroll
        for (int k = 0; k < 32; ++k) {
            float4 w = wr[k], a = ar[k];
            acc += a.x * w.x + a.y * w.y + a.z * w.z + a.w * w.w;
        }
        float u = seq[(size_t)(m0 + rr) * DD + d0] + acc;
        float s = u, q = u * u;
        wave_sum64_2(s, q);
        int wv = tid >> 6;
        if ((tid & 63) == 0) { sred[wv][0] = s; sred[wv][1] = q; }
        __syncthreads();
        int wp = rr * 2;
        s = sred[wp][0] + sred[wp + 1][0];
        q = sred[wp][1] + sred[wp + 1][1];
        float mean = s * (1.f / 128.f);
        float var = q * (1.f / 128.f) - mean * mean;
        float rstd = rsqrtf(var + 1e-5f);
        srow[rr][d0] = (u - mean) * rstd * g1[d0] + bl1[d0];
    }
    __syncthreads();
    // ---- ffn1 + relu (512 outputs x 2 rows; W row reused across rows) ----
    const float4* s0 = (const float4*)srow[0];
    const float4* s1 = (const float4*)srow[1];
#pragma unroll
    for (int rep = 0; rep < 2; ++rep) {
        int o = tid + rep * 256;
        float bv = bf1[o];
        float a0 = bv, a1 = bv;
        const float4* wr = (const float4*)&Wf1[(size_t)o * DD];
#pragma unroll
        for (int k = 0; k < 32; ++k) {
            float4 w = wr[k];
            float4 x0 = s0[k], x1 = s1[k];
            a0 += x0.x * w.x + x0.y * w.y + x0.z * w.z + x0.w * w.w;
            a1 += x1.x * w.x + x1.y * w.y + x1.z * w.z + x1.w * w.w;
        }
        f1[0][o] = fmaxf(a0, 0.f);
        f1[1][o] = fmaxf(a1, 0.f);
    }
    __syncthreads();
    // ---- ffn2 (half-split K) + residual + LN ----
    int d = tid & 127, half = tid >> 7;
    float b0 = half ? 0.f : bf2[d];
    float a0 = b0, a1 = b0;
    const float4* wr2 = (const float4*)&Wf2[(size_t)d * 512 + half * 256];
    const float4* f10 = (const float4*)&f1[0][half * 256];
    const float4* f11 = (const float4*)&f1[1][half * 256];
#pragma unroll
    for (int k = 0; k < 64; ++k) {
        float4 w = wr2[k];
        float4 x0 = f10[k], x1 = f11[k];
        a0 += x0.x * w.x + x0.y * w.y + x0.z * w.z + x0.w * w.w;
        a1 += x1.x * w.x + x1.y * w.y + x1.z * w.z + x1.w * w.w;
    }
    if (half) { pf[0][d] = a0; pf[1][d] = a1; }
    __syncthreads();
    if (half == 0) {
        float u0 = srow[0][d] + a0 + pf[0][d];
        float u1 = srow[1][d] + a1 + pf[1][d];
        float s0_ = u0, q0_ = u0 * u0, s1_ = u1, q1_ = u1 * u1;
        wave_sum64_2(s0_, q0_);
        wave_sum64_2(s1_, q1_);
        int w_ = d >> 6;
        if ((d & 63) == 0) {
            sred2[w_][0] = s0_; sred2[w_][1] = q0_;
            sred2[w_][2] = s1_; sred2[w_][3] = q1_;
        }
        __syncthreads();
        float S0 = sred2[0][0] + sred2[1][0], Q0 = sred2[0][1] + sred2[1][1];
        float S1 = sred2[0][2] + sred2[1][2], Q1 = sred2[0][3] + sred2[1][3];
        float mean0 = S0 * (1.f / 128.f);
        float var0 = Q0 * (1.f / 128.f) - mean0 * mean0;
        float rstd0 = rsqrtf(var0 + 1e-5f);
        float mean1 = S1 * (1.f / 128.f);
        float var1 = Q1 * (1.f / 128.f) - mean1 * mean1;
        float rstd1 = rsqrtf(var1 + 1e-5f);
        seq[(size_t)m0 * DD + d] = (u0 - mean0) * rstd0 * g2[d] + bl2[d];
        seq[(size_t)(m0 + 1) * DD + d] = (u1 - mean1) * rstd1 * g2[d] + bl2[d];
    } else {
        __syncthreads();
    }
}

__global__ __launch_bounds__(128) void k_head(
    const float* __restrict__ seq, const float* __restrict__ W1,
    const float* __restrict__ b1, const float* __restrict__ W2,
    const float* __restrict__ b2, float* __restrict__ out) {
    int b = blockIdx.x, t = threadIdx.x;
    __shared__ float pooled[DD];
    __shared__ float hid[64];
    float s = 0.f;
    for (int i = 0; i < TT; ++i) s += seq[(size_t)(b * TT + i) * DD + t];
    pooled[t] = s * (1.f / TT);
    __syncthreads();
    if (t < 64) {
        float a = b1[t];
        const float* wr = W1 + t * DD;
        for (int k = 0; k < DD; ++k) a += pooled[k] * wr[k];
        hid[t] = fmaxf(a, 0.f);
    }
    __syncthreads();
    if (t < 2) {
        float a = b2[t];
        const float* wr = W2 + t * 64;
        for (int k = 0; k < 64; ++k) a += hid[k] * wr[k];
        out[b * 2 + t] = a;
    }
}

// ---------------- host ----------------

extern "C" void kernel_launch(void* const* d_in, const int* in_sizes, int n_in,
                              void* d_out, int out_size, void* d_ws, size_t ws_size,
                              hipStream_t stream) {
    const float* x     = (const float*)d_in[0];
    const int*   esrc  = (const int*)d_in[1];
    const int*   edst  = (const int*)d_in[2];
    const float* gW1   = (const float*)d_in[4];
    const float* gb1   = (const float*)d_in[5];
    const float* ln1g  = (const float*)d_in[6];
    const float* ln1b  = (const float*)d_in[7];
    const float* gW2   = (const float*)d_in[8];
    const float* gb2   = (const float*)d_in[9];
    const float* ln2g  = (const float*)d_in[10];
    const float* ln2b  = (const float*)d_in[11];
    const float* gW3   = (const float*)d_in[12];
    const float* gb3   = (const float*)d_in[13];
    const float* tWqkv = (const float*)d_in[14];
    const float* tbqkv = (const float*)d_in[15];
    const float* tWo   = (const float*)d_in[16];
    const float* tbo   = (const float*)d_in[17];
    const float* tg1   = (const float*)d_in[18];
    const float* tb1   = (const float*)d_in[19];
    const float* tg2   = (const float*)d_in[20];
    const float* tb2   = (const float*)d_in[21];
    const float* tWf1  = (const float*)d_in[22];
    const float* tbf1  = (const float*)d_in[23];
    const float* tWf2  = (const float*)d_in[24];
    const float* tbf2  = (const float*)d_in[25];
    const float* hW1   = (const float*)d_in[26];
    const float* hb1   = (const float*)d_in[27];
    const float* hW2   = (const float*)d_in[28];
    const float* hb2   = (const float*)d_in[29];
    float* out = (float*)d_out;

    int*   hist   = (int*)d_ws;                 // NB_A*512
    int*   off2   = hist + NB_A * GG;           // NB_A*512
    int*   gcnt   = off2 + NB_A * GG;           // 512
    int*   goff   = gcnt + GG;                  // 516
    uint*  gpack  = (uint*)(goff + 516);        // EE
    uint2* slots  = (uint2*)(gpack + EE);       // NN*16 (16B-aligned)
    uint2* ovf    = slots + (size_t)NN * NSLOT; // GG*128
    int*   ovfcnt = (int*)(ovf + GG * 128);     // GG
    float* wgtv   = (float*)(ovfcnt + GG);      // NN
    float* pooled = wgtv + NN;                  // GG*64
    float* bufA = pooled + GG * 64;             // NN*64 (h1)
    float* seq  = bufA + (size_t)NN * 64;       // 512*128
    float* abuf = seq + GG * DD;                // 512*128

    // CSR build (no global atomics) + fused layer 1
    hipMemsetAsync(pooled, 0, GG * 64 * sizeof(float), stream);
    k_a1<<<NB_A, 256, 0, stream>>>(esrc, hist);
    k_a2a<<<GG, 64, 0, stream>>>(hist, gcnt);
    k_a2b<<<1, 512, 0, stream>>>(gcnt, goff);
    k_a2c<<<64, 512, 0, stream>>>(hist, goff, off2);
    k_a3<<<NB_A, 256, 0, stream>>>(esrc, edst, off2, gpack);
    k_bsort<<<GG, 256, 0, stream>>>(x, goff, gpack, gW1, gb1, ln1g, ln1b,
                                    slots, ovf, ovfcnt, wgtv, bufA);

    // GCN layer 2 + pooled readout (fused), then embed
    k_agg_lin_pool<<<NN / CHK, 256, 0, stream>>>(bufA, gW2, gb2, ln2g, ln2b,
                                                 slots, ovf, ovfcnt, wgtv, pooled);
    k_emb<<<GG, DD, 0, stream>>>(pooled, gW3, gb3, seq);

    // Transformer: 2 kernels per layer
    for (int l = 0; l < LL; l++) {
        k_qkv_attn<<<BB * 4, 512, 0, stream>>>(
            seq, tWqkv + (size_t)l * 384 * 128, tbqkv + l * 384, abuf);
        k_post<<<GG / 2, 256, 0, stream>>>(
            abuf, tWo + (size_t)l * 128 * 128, tbo + l * 128,
            tg1 + l * 128, tb1 + l * 128,
            tWf1 + (size_t)l * 512 * 128, tbf1 + l * 512,
            tWf2 + (size_t)l * 128 * 512, tbf2 + l * 128,
            tg2 + l * 128, tb2 + l * 128, seq);
    }

    // head
    k_head<<<BB, DD, 0, stream>>>(seq, hW1, hb1, hW2, hb2, out);
}

// Round 18
// 331.336 us; speedup vs baseline: 1.1634x; 1.1125x over previous
//
#include <hip/hip_runtime.h>

#define NN   102400
#define EE   819200
#define GG   512
#define NPG  200
#define DD   128
#define TT   64
#define BB   8
#define LL   4
#define NB_A   320     // CSR-build blocks
#define ECH_A  2560    // edges per CSR-build block (EE / NB_A)
#define SCAP 2560      // per-graph sorted-edge LDS capacity
#define NSLOT 16       // slot 0 = self, 1..15 edges, overflow list beyond
#define CHK  50        // nodes per agg chunk (4 per graph)

typedef unsigned int uint;

static __device__ __forceinline__ void wave_sum64_2(float& a, float& b) {
#pragma unroll
    for (int off = 32; off > 0; off >>= 1) {
        a += __shfl_xor(a, off, 64);
        b += __shfl_xor(b, off, 64);
    }
}

// ---------------- CSR build: coalesced two-level counting sort ----------------

__global__ __launch_bounds__(256) void k_a1(const int* __restrict__ src,
                                            int* __restrict__ hist) {
    __shared__ int h[GG];
    int tid = threadIdx.x;
    h[tid] = 0; h[tid + 256] = 0;
    __syncthreads();
    int base = blockIdx.x * ECH_A;
#pragma unroll
    for (int it = 0; it < ECH_A / 256; ++it)
        atomicAdd(&h[src[base + it * 256 + tid] / NPG], 1);
    __syncthreads();
    hist[blockIdx.x * GG + tid] = h[tid];
    hist[blockIdx.x * GG + tid + 256] = h[tid + 256];
}

__global__ __launch_bounds__(64) void k_a2a(const int* __restrict__ hist,
                                            int* __restrict__ gcnt) {
    int g = blockIdx.x, lane = threadIdx.x;
    int s = 0;
#pragma unroll
    for (int i = 0; i < NB_A / 64; ++i) s += hist[(i * 64 + lane) * GG + g];
#pragma unroll
    for (int off = 32; off > 0; off >>= 1) s += __shfl_xor(s, off, 64);
    if (lane == 0) gcnt[g] = s;
}

__global__ __launch_bounds__(512) void k_a2b(const int* __restrict__ gcnt,
                                             int* __restrict__ goff) {
    __shared__ int sm[GG];
    int g = threadIdx.x;
    int c = gcnt[g];
    sm[g] = c;
    __syncthreads();
    for (int d = 1; d < GG; d <<= 1) {
        int v = (g >= d) ? sm[g - d] : 0;
        __syncthreads();
        sm[g] += v;
        __syncthreads();
    }
    goff[g] = sm[g] - c;
    if (g == GG - 1) goff[GG] = sm[g];
}

__global__ __launch_bounds__(512) void k_a2c(const int* __restrict__ hist,
                                             const int* __restrict__ goff,
                                             int* __restrict__ off2) {
    int g = blockIdx.x * 8 + (threadIdx.x >> 6);
    int lane = threadIdx.x & 63;
    int running = goff[g];
#pragma unroll
    for (int cchunk = 0; cchunk < NB_A / 64; ++cchunk) {
        int b = cchunk * 64 + lane;
        int v = hist[b * GG + g];
        int s = v;
#pragma unroll
        for (int off = 1; off < 64; off <<= 1) {
            int t_ = __shfl_up(s, off, 64);
            if (lane >= off) s += t_;
        }
        off2[b * GG + g] = running + s - v;
        running += __shfl(s, 63, 64);
    }
}

__global__ __launch_bounds__(256) void k_a3(const int* __restrict__ src,
                                            const int* __restrict__ dst,
                                            const int* __restrict__ off2,
                                            uint* __restrict__ gpack) {
    __shared__ int cur[GG];
    int tid = threadIdx.x;
    cur[tid] = off2[blockIdx.x * GG + tid];
    cur[tid + 256] = off2[blockIdx.x * GG + tid + 256];
    __syncthreads();
    int base = blockIdx.x * ECH_A;
#pragma unroll
    for (int it = 0; it < ECH_A / 256; ++it) {
        int e = base + it * 256 + tid;
        int s = src[e], d = dst[e];
        int g = s / NPG;
        int pos = atomicAdd(&cur[g], 1);
        gpack[pos] = ((uint)(s - g * NPG) << 8) | (uint)(d - g * NPG);
    }
}

// B: per-graph in-LDS sort by dst + slot-table emit + overflow + wgt +
//    FUSED layer-1 (2-wide agg + transform + LN). Zero global atomics.
__global__ __launch_bounds__(256) void k_bsort(
    const float* __restrict__ x, const int* __restrict__ goff,
    const uint* __restrict__ gpack, const float* __restrict__ W1,
    const float* __restrict__ gb1, const float* __restrict__ lng,
    const float* __restrict__ lnb, uint2* __restrict__ slots,
    uint2* __restrict__ ovf, int* __restrict__ ovfcnt,
    float* __restrict__ wgtv, float* __restrict__ hout) {
    int g = ((blockIdx.x & 7) << 6) | (blockIdx.x >> 3);  // XCD-local graphs
    __shared__ float2 xs[NPG];
    __shared__ float2 aggl[NPG];
    __shared__ int cnt2[NPG];
    __shared__ int lnoff[NPG + 1];
    __shared__ int cur[NPG];
    __shared__ float rsq[NPG];
    __shared__ float cwl[NPG];
    __shared__ uint srec[SCAP];
    __shared__ int sm[256];
    __shared__ uint2 ovfl[128];
    __shared__ int ovfcur;
    int tid = threadIdx.x;
    int base = goff[g], E = goff[g + 1] - base;
    const float2* x2 = (const float2*)x;
    if (tid < NPG) { xs[tid] = x2[g * NPG + tid]; cnt2[tid] = 0; cwl[tid] = 0.f; }
    if (tid == 0) ovfcur = 0;
    __syncthreads();
    for (int i = tid; i < E; i += 256) atomicAdd(&cnt2[gpack[base + i] & 255u], 1);
    __syncthreads();
    int c = (tid < NPG) ? cnt2[tid] : 0;
    sm[tid] = c;
    __syncthreads();
    for (int d = 1; d < 256; d <<= 1) {
        int v = (tid >= d) ? sm[tid - d] : 0;
        __syncthreads();
        sm[tid] += v;
        __syncthreads();
    }
    if (tid < NPG) {
        lnoff[tid] = sm[tid] - c;
        cur[tid] = sm[tid] - c;
        rsq[tid] = rsqrtf((float)(c + 1));
    }
    if (tid == 0) lnoff[NPG] = E;
    __syncthreads();
    for (int i = tid; i < E; i += 256) {
        uint r = gpack[base + i];
        int pos = atomicAdd(&cur[r & 255u], 1);
        srec[pos] = r;
    }
    __syncthreads();
    for (int i = tid; i < E; i += 256) {
        uint r = srec[i];
        atomicAdd(&cwl[r >> 8], rsq[r >> 8] * rsq[r & 255u]);
    }
    __syncthreads();
    {
        uint2* sbase = &slots[(size_t)g * NPG * NSLOT];
        for (int li = tid; li < NPG * NSLOT; li += 256) {
            int n = li >> 4, s = li & 15;
            int e0 = lnoff[n];
            int En = lnoff[n + 1] - e0;
            float rd = rsq[n];
            uint2 v;
            if (s == 0) {
                v = make_uint2((uint)(g * NPG + n), __float_as_uint(rd * rd));
            } else if (s - 1 < En) {
                uint r = srec[e0 + s - 1];
                int ls = (int)(r >> 8);
                v = make_uint2((uint)(g * NPG + ls), __float_as_uint(rsq[ls] * rd));
            } else {
                v = make_uint2((uint)(g * NPG + n), 0u);
            }
            sbase[li] = v;
        }
    }
    if (tid < NPG) {
        float rd = rsq[tid];
        float dv = rd * rd;  // 1/deg
        float ax = xs[tid].x * dv, ay = xs[tid].y * dv;
        int e0 = lnoff[tid], e1 = lnoff[tid + 1];
        for (int e = e0; e < e1; ++e) {
            uint r = srec[e];
            int ls = (int)(r >> 8);
            float w = rsq[ls] * rd;
            ax += xs[ls].x * w;
            ay += xs[ls].y * w;
        }
        for (int e = e0 + NSLOT - 1; e < e1; ++e) {  // rare overflow (deg > 15)
            uint r = srec[e];
            int ls = (int)(r >> 8);
            int p = atomicAdd(&ovfcur, 1);
            if (p < 128)
                ovfl[p] = make_uint2(((uint)tid << 17) | (uint)(g * NPG + ls),
                                     __float_as_uint(rsq[ls] * rd));
        }
        aggl[tid] = make_float2(ax, ay);
        wgtv[g * NPG + tid] = cwl[tid] + dv;
    }
    __syncthreads();
    int nov = ovfcur < 128 ? ovfcur : 128;
    if (tid == 0) ovfcnt[g] = nov;
    if (tid < nov) ovf[g * 128 + tid] = ovfl[tid];
    int lane = tid & 63, wid = tid >> 6;
    float w0 = W1[lane], w1 = W1[64 + lane];
    float gbj = gb1[lane], lgj = lng[lane], lbj = lnb[lane];
    for (int i = wid; i < NPG; i += 4) {
        float2 a = aggl[i];
        float u = fmaxf(a.x * w0 + a.y * w1 + gbj, 0.f);
        float s2 = u, q2 = u * u;
        wave_sum64_2(s2, q2);
        float mean = s2 * (1.f / 64.f);
        float var = q2 * (1.f / 64.f) - mean * mean;
        hout[(size_t)(g * NPG + i) * 64 + lane] = (u - mean) * rsqrtf(var + 1e-5f) * lgj + lbj;
    }
}

// ---------------- GCN layer 2 + pooled readout, fused ----------------

__global__ __launch_bounds__(256) void k_agg_lin_pool(
    const float* __restrict__ t, const float* __restrict__ W,
    const float* __restrict__ gb, const float* __restrict__ lng,
    const float* __restrict__ lnb, const uint2* __restrict__ slots,
    const uint2* __restrict__ ovf, const int* __restrict__ ovfcnt,
    const float* __restrict__ wgtv, float* __restrict__ pooled) {
    int c = ((blockIdx.x & 7) << 8) | (blockIdx.x >> 3);
    int n0 = c * CHK;
    int g = c >> 2, lbase = (c & 3) * CHK;
    __shared__ float hs[CHK][64];
    __shared__ uint2 slt[CHK][NSLOT];
    __shared__ float wgt[CHK];
    __shared__ float red[4][64];
    int tid = threadIdx.x, lane = tid & 63, wid = tid >> 6;
    int grp = lane >> 4, fq = lane & 15;
    // W register cache first: 64 independent loads overlap the staging below
    float wreg[64];
#pragma unroll
    for (int k = 0; k < 64; ++k) wreg[k] = W[k * 64 + lane];
    {   // stage slot table (coalesced)
        const float4* s4 = (const float4*)&slots[(size_t)n0 * NSLOT];
        float4* d4 = (float4*)slt;
        for (int i = tid; i < CHK * NSLOT / 2; i += 256) d4[i] = s4[i];
    }
    if (tid < CHK) wgt[tid] = wgtv[n0 + tid];
    __syncthreads();
#pragma unroll 2
    for (int i = wid; i < CHK; i += 4) {
        float4 acc = make_float4(0.f, 0.f, 0.f, 0.f);
#pragma unroll
        for (int r = 0; r < 4; ++r) {            // fully static: 16 slots
            uint2 s = slt[i][r * 4 + grp];
            float w = __uint_as_float(s.y);
            float4 tv = *(const float4*)&t[(size_t)s.x * 64 + fq * 4];
            acc.x += tv.x * w; acc.y += tv.y * w;
            acc.z += tv.z * w; acc.w += tv.w * w;
        }
        acc.x += __shfl_xor(acc.x, 16); acc.y += __shfl_xor(acc.y, 16);
        acc.z += __shfl_xor(acc.z, 16); acc.w += __shfl_xor(acc.w, 16);
        acc.x += __shfl_xor(acc.x, 32); acc.y += __shfl_xor(acc.y, 32);
        acc.z += __shfl_xor(acc.z, 32); acc.w += __shfl_xor(acc.w, 32);
        if (grp == 0) *(float4*)&hs[i][fq * 4] = acc;
    }
    __syncthreads();
    int nov = ovfcnt[g];
    if (nov && wid == 0) {  // rare overflow edges
        for (int k = 0; k < nov; ++k) {
            uint2 r = ovf[g * 128 + k];
            int ld = r.x >> 17;
            if (ld >= lbase && ld < lbase + CHK)
                hs[ld - lbase][lane] +=
                    t[(size_t)(r.x & 0x1FFFFu) * 64 + lane] * __uint_as_float(r.y);
        }
    }
    __syncthreads();
    float gbj = gb[lane], lgj = lng[lane], lbj = lnb[lane];
    float psum = 0.f;
    for (int i = wid; i < CHK; i += 4) {
        const float4* hrow = (const float4*)&hs[i][0];
        float a0 = 0.f, a1 = 0.f;
#pragma unroll
        for (int k4 = 0; k4 < 16; k4 += 2) {
            float4 h0 = hrow[k4], h1 = hrow[k4 + 1];
            a0 += h0.x * wreg[4 * k4] + h0.y * wreg[4 * k4 + 1] +
                  h0.z * wreg[4 * k4 + 2] + h0.w * wreg[4 * k4 + 3];
            a1 += h1.x * wreg[4 * k4 + 4] + h1.y * wreg[4 * k4 + 5] +
                  h1.z * wreg[4 * k4 + 6] + h1.w * wreg[4 * k4 + 7];
        }
        float u = fmaxf(a0 + a1 + gbj, 0.f);
        float s = u, q = u * u;
        wave_sum64_2(s, q);
        float mean = s * (1.f / 64.f);
        float var = q * (1.f / 64.f) - mean * mean;
        float h = (u - mean) * rsqrtf(var + 1e-5f) * lgj + lbj;
        psum += h * wgt[i];
    }
    red[wid][lane] = psum;
    __syncthreads();
    if (tid < 64)
        atomicAdd(&pooled[g * 64 + tid],
                  red[0][tid] + red[1][tid] + red[2][tid] + red[3][tid]);
}

// pooled(64) @ W3 -> 128 + b3 + PE -> seq[g][d]
__global__ __launch_bounds__(128) void k_emb(
    const float* __restrict__ pooled, const float* __restrict__ W3,
    const float* __restrict__ b3, float* __restrict__ seq) {
    int g = blockIdx.x, d = threadIdx.x;
    __shared__ float ps[64];
    if (d < 64) ps[d] = pooled[g * 64 + d] * (1.f / NPG);
    __syncthreads();
    float a = b3[d];
#pragma unroll 8
    for (int k = 0; k < 64; ++k) a += ps[k] * W3[k * DD + d];
    float freq = expf((float)(d & ~1) * (-9.210340371976184f / 128.f));
    float ang = (float)(g & (TT - 1)) * freq;
    a += (d & 1) ? cosf(ang) : sinf(ang);
    seq[(size_t)g * DD + d] = a;
}

// ---------------- Transformer ----------------

// qkv: one seq row per block, 3 outputs per thread
__global__ __launch_bounds__(128) void k_qkv(
    const float* __restrict__ seq, const float* __restrict__ Wqkv,
    const float* __restrict__ bqkv, float* __restrict__ qkvb) {
    int m = blockIdx.x, tid = threadIdx.x;
    __shared__ float row[128];
    row[tid] = seq[(size_t)m * DD + tid];
    __syncthreads();
    const float4* r4 = (const float4*)row;
    float acc0 = bqkv[tid], acc1 = bqkv[tid + 128], acc2 = bqkv[tid + 256];
    const float4* w0 = (const float4*)&Wqkv[(size_t)tid * DD];
    const float4* w1 = (const float4*)&Wqkv[(size_t)(tid + 128) * DD];
    const float4* w2 = (const float4*)&Wqkv[(size_t)(tid + 256) * DD];
#pragma unroll
    for (int k = 0; k < 32; ++k) {
        float4 a = r4[k];
        float4 x0 = w0[k], x1 = w1[k], x2 = w2[k];
        acc0 += a.x * x0.x + a.y * x0.y + a.z * x0.z + a.w * x0.w;
        acc1 += a.x * x1.x + a.y * x1.y + a.z * x1.z + a.w * x1.w;
        acc2 += a.x * x2.x + a.y * x2.y + a.z * x2.z + a.w * x2.w;
    }
    float* ob = qkvb + (size_t)m * 384;
    ob[tid] = acc0;
    ob[tid + 128] = acc1;
    ob[tid + 256] = acc2;
}

// attention: block = (b, h, q-quad of 16), 256 threads
__global__ __launch_bounds__(256) void k_attn(const float* __restrict__ qkvb,
                                              float* __restrict__ abuf) {
    int bh = blockIdx.x >> 2, quad = blockIdx.x & 3;
    int b = bh >> 2, h = bh & 3;
    __shared__ float Ks[64][36], Vs[64][36];
    __shared__ float Ss[16][68];
    int tid = threadIdx.x;
    const float* base = qkvb + (size_t)(b * 64) * 384 + h * 32;
    for (int li = tid; li < 512; li += 256) {
        int r = li >> 3, cc = li & 7;
        *(float4*)&Ks[r][cc * 4] = *(const float4*)&base[(size_t)r * 384 + 128 + cc * 4];
        *(float4*)&Vs[r][cc * 4] = *(const float4*)&base[(size_t)r * 384 + 256 + cc * 4];
    }
    __syncthreads();
    int ql = tid >> 4, kl = tid & 15;       // 16 queries x 16 k-lanes
    int q = quad * 16 + ql;
    float qreg[32];
    {
        const float4* qp = (const float4*)&base[(size_t)q * 384];
#pragma unroll
        for (int i = 0; i < 8; ++i) {
            float4 v = qp[i];
            qreg[i * 4] = v.x; qreg[i * 4 + 1] = v.y;
            qreg[i * 4 + 2] = v.z; qreg[i * 4 + 3] = v.w;
        }
    }
    const float scale = 0.17677669529663687f;  // 1/sqrt(32)
    float p[4];
    float mx = -1e30f;
#pragma unroll
    for (int kk = 0; kk < 4; ++kk) {
        int k = kl * 4 + kk;
        float a = 0.f;
#pragma unroll
        for (int d = 0; d < 32; ++d) a += qreg[d] * Ks[k][d];
        p[kk] = a * scale;
        mx = fmaxf(mx, p[kk]);
    }
    mx = fmaxf(mx, __shfl_xor(mx, 1));
    mx = fmaxf(mx, __shfl_xor(mx, 2));
    mx = fmaxf(mx, __shfl_xor(mx, 4));
    mx = fmaxf(mx, __shfl_xor(mx, 8));
    float ssum = 0.f;
#pragma unroll
    for (int kk = 0; kk < 4; ++kk) {
        p[kk] = expf(p[kk] - mx);
        ssum += p[kk];
    }
    ssum += __shfl_xor(ssum, 1);
    ssum += __shfl_xor(ssum, 2);
    ssum += __shfl_xor(ssum, 4);
    ssum += __shfl_xor(ssum, 8);
    float inv = 1.f / ssum;
#pragma unroll
    for (int kk = 0; kk < 4; ++kk) Ss[ql][kl * 4 + kk] = p[kk] * inv;
    __syncthreads();
    int d0 = kl * 2;
    float o0 = 0.f, o1 = 0.f;
#pragma unroll 4
    for (int k = 0; k < 64; ++k) {
        float pw = Ss[ql][k];
        o0 += pw * Vs[k][d0];
        o1 += pw * Vs[k][d0 + 1];
    }
    float* op = abuf + (size_t)(b * 64 + q) * DD + h * 32 + d0;
    op[0] = o0;
    op[1] = o1;
}

// proj + LN + ffn1 + relu + ffn2 + residual + LN — fully row-local, 2 rows/block
__global__ __launch_bounds__(256) void k_post(
    const float* __restrict__ abuf, const float* __restrict__ Wo,
    const float* __restrict__ bo, const float* __restrict__ g1,
    const float* __restrict__ bl1, const float* __restrict__ Wf1,
    const float* __restrict__ bf1, const float* __restrict__ Wf2,
    const float* __restrict__ bf2, const float* __restrict__ g2,
    const float* __restrict__ bl2, float* __restrict__ seq) {
    int m0 = blockIdx.x * 2, tid = threadIdx.x;
    __shared__ float arow[2][128];
    __shared__ float srow[2][128];
    __shared__ float f1[2][512];
    __shared__ float pf[2][128];
    __shared__ float sred[4][2];
    __shared__ float sred2[2][4];
    int rr = tid >> 7, d0 = tid & 127;
    arow[rr][d0] = abuf[(size_t)(m0 + rr) * DD + d0];
    __syncthreads();
    {
        float acc = bo[d0];
        const float4* wr = (const float4*)&Wo[(size_t)d0 * DD];
        const float4* ar = (const float4*)arow[rr];
#pragma unroll
        for (int k = 0; k < 32; ++k) {
            float4 w = wr[k], a = ar[k];
            acc += a.x * w.x + a.y * w.y + a.z * w.z + a.w * w.w;
        }
        float u = seq[(size_t)(m0 + rr) * DD + d0] + acc;
        float s = u, q = u * u;
        wave_sum64_2(s, q);
        int wv = tid >> 6;
        if ((tid & 63) == 0) { sred[wv][0] = s; sred[wv][1] = q; }
        __syncthreads();
        int wp = rr * 2;
        s = sred[wp][0] + sred[wp + 1][0];
        q = sred[wp][1] + sred[wp + 1][1];
        float mean = s * (1.f / 128.f);
        float var = q * (1.f / 128.f) - mean * mean;
        float rstd = rsqrtf(var + 1e-5f);
        srow[rr][d0] = (u - mean) * rstd * g1[d0] + bl1[d0];
    }
    __syncthreads();
    const float4* s0 = (const float4*)srow[0];
    const float4* s1 = (const float4*)srow[1];
#pragma unroll
    for (int rep = 0; rep < 2; ++rep) {
        int o = tid + rep * 256;
        float bv = bf1[o];
        float a0 = bv, a1 = bv;
        const float4* wr = (const float4*)&Wf1[(size_t)o * DD];
#pragma unroll
        for (int k = 0; k < 32; ++k) {
            float4 w = wr[k];
            float4 x0 = s0[k], x1 = s1[k];
            a0 += x0.x * w.x + x0.y * w.y + x0.z * w.z + x0.w * w.w;
            a1 += x1.x * w.x + x1.y * w.y + x1.z * w.z + x1.w * w.w;
        }
        f1[0][o] = fmaxf(a0, 0.f);
        f1[1][o] = fmaxf(a1, 0.f);
    }
    __syncthreads();
    int d = tid & 127, half = tid >> 7;
    float b0 = half ? 0.f : bf2[d];
    float a0 = b0, a1 = b0;
    const float4* wr2 = (const float4*)&Wf2[(size_t)d * 512 + half * 256];
    const float4* f10 = (const float4*)&f1[0][half * 256];
    const float4* f11 = (const float4*)&f1[1][half * 256];
#pragma unroll
    for (int k = 0; k < 64; ++k) {
        float4 w = wr2[k];
        float4 x0 = f10[k], x1 = f11[k];
        a0 += x0.x * w.x + x0.y * w.y + x0.z * w.z + x0.w * w.w;
        a1 += x1.x * w.x + x1.y * w.y + x1.z * w.z + x1.w * w.w;
    }
    if (half) { pf[0][d] = a0; pf[1][d] = a1; }
    __syncthreads();
    if (half == 0) {
        float u0 = srow[0][d] + a0 + pf[0][d];
        float u1 = srow[1][d] + a1 + pf[1][d];
        float s0_ = u0, q0_ = u0 * u0, s1_ = u1, q1_ = u1 * u1;
        wave_sum64_2(s0_, q0_);
        wave_sum64_2(s1_, q1_);
        int w_ = d >> 6;
        if ((d & 63) == 0) {
            sred2[w_][0] = s0_; sred2[w_][1] = q0_;
            sred2[w_][2] = s1_; sred2[w_][3] = q1_;
        }
        __syncthreads();
        float S0 = sred2[0][0] + sred2[1][0], Q0 = sred2[0][1] + sred2[1][1];
        float S1 = sred2[0][2] + sred2[1][2], Q1 = sred2[0][3] + sred2[1][3];
        float mean0 = S0 * (1.f / 128.f);
        float var0 = Q0 * (1.f / 128.f) - mean0 * mean0;
        float rstd0 = rsqrtf(var0 + 1e-5f);
        float mean1 = S1 * (1.f / 128.f);
        float var1 = Q1 * (1.f / 128.f) - mean1 * mean1;
        float rstd1 = rsqrtf(var1 + 1e-5f);
        seq[(size_t)m0 * DD + d] = (u0 - mean0) * rstd0 * g2[d] + bl2[d];
        seq[(size_t)(m0 + 1) * DD + d] = (u1 - mean1) * rstd1 * g2[d] + bl2[d];
    } else {
        __syncthreads();
    }
}

__global__ __launch_bounds__(128) void k_head(
    const float* __restrict__ seq, const float* __restrict__ W1,
    const float* __restrict__ b1, const float* __restrict__ W2,
    const float* __restrict__ b2, float* __restrict__ out) {
    int b = blockIdx.x, t = threadIdx.x;
    __shared__ float pooled[DD];
    __shared__ float hid[64];
    float s = 0.f;
    for (int i = 0; i < TT; ++i) s += seq[(size_t)(b * TT + i) * DD + t];
    pooled[t] = s * (1.f / TT);
    __syncthreads();
    if (t < 64) {
        float a = b1[t];
        const float* wr = W1 + t * DD;
        for (int k = 0; k < DD; ++k) a += pooled[k] * wr[k];
        hid[t] = fmaxf(a, 0.f);
    }
    __syncthreads();
    if (t < 2) {
        float a = b2[t];
        const float* wr = W2 + t * 64;
        for (int k = 0; k < 64; ++k) a += hid[k] * wr[k];
        out[b * 2 + t] = a;
    }
}

// ---------------- host ----------------

extern "C" void kernel_launch(void* const* d_in, const int* in_sizes, int n_in,
                              void* d_out, int out_size, void* d_ws, size_t ws_size,
                              hipStream_t stream) {
    const float* x     = (const float*)d_in[0];
    const int*   esrc  = (const int*)d_in[1];
    const int*   edst  = (const int*)d_in[2];
    const float* gW1   = (const float*)d_in[4];
    const float* gb1   = (const float*)d_in[5];
    const float* ln1g  = (const float*)d_in[6];
    const float* ln1b  = (const float*)d_in[7];
    const float* gW2   = (const float*)d_in[8];
    const float* gb2   = (const float*)d_in[9];
    const float* ln2g  = (const float*)d_in[10];
    const float* ln2b  = (const float*)d_in[11];
    const float* gW3   = (const float*)d_in[12];
    const float* gb3   = (const float*)d_in[13];
    const float* tWqkv = (const float*)d_in[14];
    const float* tbqkv = (const float*)d_in[15];
    const float* tWo   = (const float*)d_in[16];
    const float* tbo   = (const float*)d_in[17];
    const float* tg1   = (const float*)d_in[18];
    const float* tb1   = (const float*)d_in[19];
    const float* tg2   = (const float*)d_in[20];
    const float* tb2   = (const float*)d_in[21];
    const float* tWf1  = (const float*)d_in[22];
    const float* tbf1  = (const float*)d_in[23];
    const float* tWf2  = (const float*)d_in[24];
    const float* tbf2  = (const float*)d_in[25];
    const float* hW1   = (const float*)d_in[26];
    const float* hb1   = (const float*)d_in[27];
    const float* hW2   = (const float*)d_in[28];
    const float* hb2   = (const float*)d_in[29];
    float* out = (float*)d_out;

    int*   hist   = (int*)d_ws;                 // NB_A*512
    int*   off2   = hist + NB_A * GG;           // NB_A*512
    int*   gcnt   = off2 + NB_A * GG;           // 512
    int*   goff   = gcnt + GG;                  // 516
    uint*  gpack  = (uint*)(goff + 516);        // EE
    uint2* slots  = (uint2*)(gpack + EE);       // NN*16 (16B-aligned)
    uint2* ovf    = slots + (size_t)NN * NSLOT; // GG*128
    int*   ovfcnt = (int*)(ovf + GG * 128);     // GG
    float* wgtv   = (float*)(ovfcnt + GG);      // NN
    float* pooled = wgtv + NN;                  // GG*64
    float* bufA = pooled + GG * 64;             // NN*64 (h1)
    float* seq  = bufA + (size_t)NN * 64;       // 512*128
    float* qkvb = seq + GG * DD;                // 512*384
    float* abuf = qkvb + GG * 384;              // 512*128

    // CSR build (no global atomics) + fused layer 1
    hipMemsetAsync(pooled, 0, GG * 64 * sizeof(float), stream);
    k_a1<<<NB_A, 256, 0, stream>>>(esrc, hist);
    k_a2a<<<GG, 64, 0, stream>>>(hist, gcnt);
    k_a2b<<<1, 512, 0, stream>>>(gcnt, goff);
    k_a2c<<<64, 512, 0, stream>>>(hist, goff, off2);
    k_a3<<<NB_A, 256, 0, stream>>>(esrc, edst, off2, gpack);
    k_bsort<<<GG, 256, 0, stream>>>(x, goff, gpack, gW1, gb1, ln1g, ln1b,
                                    slots, ovf, ovfcnt, wgtv, bufA);

    // GCN layer 2 + pooled readout (fused), then embed
    k_agg_lin_pool<<<NN / CHK, 256, 0, stream>>>(bufA, gW2, gb2, ln2g, ln2b,
                                                 slots, ovf, ovfcnt, wgtv, pooled);
    k_emb<<<GG, DD, 0, stream>>>(pooled, gW3, gb3, seq);

    // Transformer: 3 kernels per layer (qkv and attn parallelized)
    for (int l = 0; l < LL; l++) {
        k_qkv<<<GG, 128, 0, stream>>>(
            seq, tWqkv + (size_t)l * 384 * 128, tbqkv + l * 384, qkvb);
        k_attn<<<BB * 4 * 4, 256, 0, stream>>>(qkvb, abuf);
        k_post<<<GG / 2, 256, 0, stream>>>(
            abuf, tWo + (size_t)l * 128 * 128, tbo + l * 128,
            tg1 + l * 128, tb1 + l * 128,
            tWf1 + (size_t)l * 512 * 128, tbf1 + l * 512,
            tWf2 + (size_t)l * 128 * 512, tbf2 + l * 128,
            tg2 + l * 128, tb2 + l * 128, seq);
    }

    // head
    k_head<<<BB, DD, 0, stream>>>(seq, hW1, hb1, hW2, hb2, out);
}